// Round 1
// baseline (5538.156 us; speedup 1.0000x reference)
//
#include <hip/hip_runtime.h>

// Softmax splatting (softsplat, soft mode), fp32.
// B=4, C=16, H=512, W=960.
//
// Stage 1: zero accumulators (hipMemsetAsync).
// Stage 2: splat kernel — one thread per source pixel; 4 corners x (C+1) atomicAdds.
//          Value channels accumulate in d_out [B,C,H,W]; weight channel in d_ws [B,H,W].
// Stage 3: normalize — out /= (w + EPS).

#define BB 4
#define CC 16
#define HH 512
#define WW 960
#define HWPROD (HH * WW)
#define EPSF 1e-7f

__global__ void splat_kernel(const float* __restrict__ in,
                             const float* __restrict__ flow,
                             const float* __restrict__ metric,
                             float* __restrict__ out,   // [B,C,H,W] accumulator
                             float* __restrict__ wbuf)  // [B,H,W]   weight accumulator
{
    int idx = blockIdx.x * blockDim.x + threadIdx.x;
    if (idx >= BB * HWPROD) return;
    int b = idx / HWPROD;
    int p = idx - b * HWPROD;
    int y = p / WW;
    int x = p - y * WW;

    float dx = flow[(size_t)(b * 2 + 0) * HWPROD + p];
    float dy = flow[(size_t)(b * 2 + 1) * HWPROD + p];
    float m  = expf(metric[(size_t)b * HWPROD + p]);

    float fx = (float)x + dx;
    float fy = (float)y + dy;
    float x0f = floorf(fx), y0f = floorf(fy);
    int   x0  = (int)x0f,   y0  = (int)y0f;
    float wx1 = fx - x0f,   wy1 = fy - y0f;
    float wx0 = 1.0f - wx1, wy0 = 1.0f - wy1;

    // Load and premultiply the 16 channel values (coalesced: stride HWPROD).
    float v[CC];
    const float* inp = in + (size_t)b * CC * HWPROD + p;
#pragma unroll
    for (int c = 0; c < CC; ++c) v[c] = inp[(size_t)c * HWPROD] * m;

    const int   xs[4] = { x0,     x0 + 1, x0,     x0 + 1 };
    const int   ys[4] = { y0,     y0,     y0 + 1, y0 + 1 };
    const float ws[4] = { wx0 * wy0, wx1 * wy0, wx0 * wy1, wx1 * wy1 };

#pragma unroll
    for (int k = 0; k < 4; ++k) {
        int xi = xs[k], yi = ys[k];
        if (xi >= 0 && xi < WW && yi >= 0 && yi < HH) {
            float wgt = ws[k];
            int   tp  = yi * WW + xi;
            atomicAdd(&wbuf[(size_t)b * HWPROD + tp], m * wgt);
            float* op = out + (size_t)b * CC * HWPROD + tp;
#pragma unroll
            for (int c = 0; c < CC; ++c)
                atomicAdd(&op[(size_t)c * HWPROD], v[c] * wgt);
        }
    }
}

__global__ void norm_kernel(float* __restrict__ out,
                            const float* __restrict__ wbuf)
{
    int idx = blockIdx.x * blockDim.x + threadIdx.x;
    if (idx >= BB * HWPROD) return;
    int b = idx / HWPROD;
    int p = idx - b * HWPROD;

    float inv = 1.0f / (wbuf[(size_t)b * HWPROD + p] + EPSF);
    float* op = out + (size_t)b * CC * HWPROD + p;
#pragma unroll
    for (int c = 0; c < CC; ++c)
        op[(size_t)c * HWPROD] *= inv;
}

extern "C" void kernel_launch(void* const* d_in, const int* in_sizes, int n_in,
                              void* d_out, int out_size, void* d_ws, size_t ws_size,
                              hipStream_t stream) {
    const float* in     = (const float*)d_in[0];
    const float* flow   = (const float*)d_in[1];
    const float* metric = (const float*)d_in[2];
    float* out  = (float*)d_out;
    float* wbuf = (float*)d_ws;

    // Zero accumulators (harness re-poisons with 0xAA before every launch).
    hipMemsetAsync(out,  0, sizeof(float) * (size_t)BB * CC * HWPROD, stream);
    hipMemsetAsync(wbuf, 0, sizeof(float) * (size_t)BB * HWPROD,      stream);

    int n = BB * HWPROD;
    dim3 blk(256);
    dim3 grd((n + 255) / 256);
    splat_kernel<<<grd, blk, 0, stream>>>(in, flow, metric, out, wbuf);
    norm_kernel<<<grd, blk, 0, stream>>>(out, wbuf);
}

// Round 2
// 1656.794 us; speedup vs baseline: 3.3427x; 3.3427x over previous
//
#include <hip/hip_runtime.h>

// Softmax splatting (softsplat, soft mode), fp32. B=4, C=16, H=512, W=960.
//
// Two-phase binned splat — removes all global scattered atomics:
//   P0: memset per-tile counters (7.7 KB).
//   P1: bin_kernel — per source pixel, append packed (x,y) to each 32x32
//       target tile overlapped by its 2x2 corner square (counter atomics only).
//   P2: tile_kernel — one block per tile; accumulate 32x32x17 patch in LDS
//       (ds_add atomics), gather source channels/flow/metric via bins,
//       then dense coalesced writeback fused with normalization.

#define BB 4
#define CC 16
#define HH 512
#define WW 960
#define HWPROD (HH * WW)
#define EPSF 1e-7f

#define TS 32                       // tile side
#define TX (WW / TS)                // 30 tiles in x
#define TY (HH / TS)                // 16 tiles in y
#define NTILE (BB * TX * TY)        // 1920 tiles
#define CAP 3072                    // per-tile bin capacity (mean ~1090)

__global__ void bin_kernel(const float* __restrict__ flow,
                           unsigned int* __restrict__ counts,
                           unsigned int* __restrict__ bins)
{
    int idx = blockIdx.x * blockDim.x + threadIdx.x;
    if (idx >= BB * HWPROD) return;
    int b = idx / HWPROD;
    int p = idx - b * HWPROD;
    int y = p / WW;
    int x = p - y * WW;

    float dx = flow[(size_t)(b * 2 + 0) * HWPROD + p];
    float dy = flow[(size_t)(b * 2 + 1) * HWPROD + p];
    int x0 = (int)floorf((float)x + dx);
    int y0 = (int)floorf((float)y + dy);

    // tiles overlapped by the 2x2 corner square {x0,x0+1} x {y0,y0+1}
    int txA = x0 >> 5, txB = (x0 + 1) >> 5;   // arithmetic shift = floor div
    int tyA = y0 >> 5, tyB = (y0 + 1) >> 5;

    unsigned int e = ((unsigned int)y << 10) | (unsigned int)x;
    int tbase = b * (TX * TY);

    #define INSERT(tx_, ty_)                                                   \
        if ((tx_) >= 0 && (tx_) < TX && (ty_) >= 0 && (ty_) < TY) {            \
            int t_ = tbase + (ty_) * TX + (tx_);                               \
            unsigned int i_ = atomicAdd(&counts[t_], 1u);                      \
            if (i_ < CAP) bins[(size_t)t_ * CAP + i_] = e;                     \
        }

    INSERT(txA, tyA);
    if (txB != txA)                 INSERT(txB, tyA);
    if (tyB != tyA)                 INSERT(txA, tyB);
    if (txB != txA && tyB != tyA)   INSERT(txB, tyB);
    #undef INSERT
}

__launch_bounds__(256)
__global__ void tile_kernel(const float* __restrict__ in,
                            const float* __restrict__ flow,
                            const float* __restrict__ metric,
                            const unsigned int* __restrict__ counts,
                            const unsigned int* __restrict__ bins,
                            float* __restrict__ out)
{
    __shared__ float acc[TS * TS * 17];   // 69632 B: [pixel][c0..c15, w]

    int tile = blockIdx.x;
    int b  = tile / (TX * TY);
    int t  = tile - b * (TX * TY);
    int ty = t / TX;
    int tx = t - ty * TX;
    int tid = threadIdx.x;

    for (int i = tid; i < TS * TS * 17; i += 256) acc[i] = 0.0f;
    __syncthreads();

    unsigned int n = counts[tile];
    if (n > CAP) n = CAP;

    for (unsigned int base = 0; base < n; base += 256) {
        unsigned int i = base + tid;
        if (i < n) {
            unsigned int e = bins[(size_t)tile * CAP + i];
            int x = (int)(e & 1023u);
            int y = (int)(e >> 10);
            int p = y * WW + x;

            float dx = flow[(size_t)(b * 2 + 0) * HWPROD + p];
            float dy = flow[(size_t)(b * 2 + 1) * HWPROD + p];
            float m  = expf(metric[(size_t)b * HWPROD + p]);

            float fx = (float)x + dx;
            float fy = (float)y + dy;
            float x0f = floorf(fx), y0f = floorf(fy);
            int   x0  = (int)x0f,   y0  = (int)y0f;
            float wx1 = fx - x0f,   wy1 = fy - y0f;
            float wx0 = 1.0f - wx1, wy0 = 1.0f - wy1;

            float v[CC];
            const float* inp = in + (size_t)b * CC * HWPROD + p;
#pragma unroll
            for (int c = 0; c < CC; ++c) v[c] = inp[(size_t)c * HWPROD] * m;

            const int   xs[4] = { x0,        x0 + 1,    x0,        x0 + 1    };
            const int   ys[4] = { y0,        y0,        y0 + 1,    y0 + 1    };
            const float ws[4] = { wx0 * wy0, wx1 * wy0, wx0 * wy1, wx1 * wy1 };

#pragma unroll
            for (int k = 0; k < 4; ++k) {
                int xi = xs[k], yi = ys[k];
                // tile-membership check doubles as image-bounds check
                if ((xi >> 5) == tx && (yi >> 5) == ty) {
                    float wgt = ws[k];
                    int q = ((yi & 31) * TS + (xi & 31)) * 17;
#pragma unroll
                    for (int c = 0; c < CC; ++c)
                        atomicAdd(&acc[q + c], v[c] * wgt);
                    atomicAdd(&acc[q + CC], m * wgt);
                }
            }
        }
    }
    __syncthreads();

    // Dense writeback + fused normalization. Tiles partition the image.
    for (int q = tid; q < TS * TS; q += 256) {
        int ly = q >> 5, lx = q & 31;
        int gp = (ty * TS + ly) * WW + tx * TS + lx;
        float inv = 1.0f / (acc[q * 17 + CC] + EPSF);
        float* op = out + (size_t)b * CC * HWPROD + gp;
#pragma unroll
        for (int c = 0; c < CC; ++c)
            op[(size_t)c * HWPROD] = acc[q * 17 + c] * inv;
    }
}

extern "C" void kernel_launch(void* const* d_in, const int* in_sizes, int n_in,
                              void* d_out, int out_size, void* d_ws, size_t ws_size,
                              hipStream_t stream) {
    const float* in     = (const float*)d_in[0];
    const float* flow   = (const float*)d_in[1];
    const float* metric = (const float*)d_in[2];
    float* out = (float*)d_out;

    unsigned int* counts = (unsigned int*)d_ws;                 // 1920 u32
    unsigned int* bins   = (unsigned int*)((char*)d_ws + 8192); // 1920*CAP u32

    hipMemsetAsync(counts, 0, NTILE * sizeof(unsigned int), stream);

    int n = BB * HWPROD;
    bin_kernel<<<dim3((n + 255) / 256), dim3(256), 0, stream>>>(flow, counts, bins);
    tile_kernel<<<dim3(NTILE), dim3(256), 0, stream>>>(in, flow, metric, counts, bins, out);
}

// Round 3
// 877.071 us; speedup vs baseline: 6.3144x; 1.8890x over previous
//
#include <hip/hip_runtime.h>

// Softmax splatting (softsplat, soft mode), fp32. B=4, C=16, H=512, W=960.
//
// P1: bin_kernel — 2D 32x8 source patch per block; per-block LDS count table
//     (960 tiles of its batch), ONE global returning-atomic per (block,tile),
//     contiguous run writes into bins (entries grouped by source patch).
// P2: tile_kernel — one block per 32x16 target tile; accumulate 32x16x17
//     patch in LDS (ds atomics, 34.8 KB -> 4 blocks/CU), gather sources via
//     bins, dense coalesced writeback fused with normalization.

#define BB 4
#define CC 16
#define HH 512
#define WW 960
#define HWPROD (HH * WW)
#define EPSF 1e-7f

#define TSX 32
#define TSY 16
#define TNX (WW / TSX)              // 30
#define TNY (HH / TSY)              // 32
#define TPB (TNX * TNY)             // 960 tiles per batch
#define NTILE (BB * TPB)            // 3840
#define CAP 1536                    // per-tile capacity (mean ~600)

__launch_bounds__(256)
__global__ void bin_kernel(const float* __restrict__ flow,
                           unsigned int* __restrict__ counts,
                           unsigned int* __restrict__ bins)
{
    __shared__ unsigned int lcnt[TPB];   // phase1: local count; phase2: global base

    int b  = blockIdx.z;
    int x  = blockIdx.x * 32 + (threadIdx.x & 31);
    int y  = blockIdx.y * 8  + (threadIdx.x >> 5);
    int p  = y * WW + x;

    for (int i = threadIdx.x; i < TPB; i += 256) lcnt[i] = 0;
    __syncthreads();

    float dx = flow[(size_t)(b * 2 + 0) * HWPROD + p];
    float dy = flow[(size_t)(b * 2 + 1) * HWPROD + p];
    int x0 = (int)floorf((float)x + dx);
    int y0 = (int)floorf((float)y + dy);

    int txA = x0 >> 5, txB = (x0 + 1) >> 5;
    int tyA = y0 >> 4, tyB = (y0 + 1) >> 4;

    int          tA[4];
    unsigned int rA[4];
    int cnt = 0;

    #define TRYINS(tx_, ty_)                                                   \
        if ((tx_) >= 0 && (tx_) < TNX && (ty_) >= 0 && (ty_) < TNY) {          \
            int t_ = (ty_) * TNX + (tx_);                                      \
            rA[cnt] = atomicAdd(&lcnt[t_], 1u);                                \
            tA[cnt] = t_;                                                      \
            ++cnt;                                                             \
        }

    TRYINS(txA, tyA);
    if (txB != txA) TRYINS(txB, tyA);
    if (tyB != tyA) {
        TRYINS(txA, tyB);
        if (txB != txA) TRYINS(txB, tyB);
    }
    #undef TRYINS

    __syncthreads();

    // Allocate one contiguous global run per nonempty tile; store base in lcnt.
    for (int i = threadIdx.x; i < TPB; i += 256) {
        unsigned int c = lcnt[i];
        if (c) lcnt[i] = atomicAdd(&counts[b * TPB + i], c);
    }
    __syncthreads();

    unsigned int e = ((unsigned int)y << 10) | (unsigned int)x;
    for (int k = 0; k < cnt; ++k) {
        int t_ = tA[k];
        unsigned int pos = lcnt[t_] + rA[k];
        if (pos < CAP)
            bins[((size_t)(b * TPB) + t_) * CAP + pos] = e;
    }
}

__launch_bounds__(256)
__global__ void tile_kernel(const float* __restrict__ in,
                            const float* __restrict__ flow,
                            const float* __restrict__ metric,
                            const unsigned int* __restrict__ counts,
                            const unsigned int* __restrict__ bins,
                            float* __restrict__ out)
{
    __shared__ float acc[TSX * TSY * 17];   // 34816 B: [pixel][c0..c15, w]

    int tile = blockIdx.x;
    int b  = tile / TPB;
    int t  = tile - b * TPB;
    int ty = t / TNX;
    int tx = t - ty * TNX;
    int tid = threadIdx.x;

    for (int i = tid; i < TSX * TSY * 17; i += 256) acc[i] = 0.0f;
    __syncthreads();

    unsigned int n = counts[tile];
    if (n > CAP) n = CAP;

    for (unsigned int base = 0; base < n; base += 256) {
        unsigned int i = base + tid;
        if (i < n) {
            unsigned int e = bins[(size_t)tile * CAP + i];
            int x = (int)(e & 1023u);
            int y = (int)(e >> 10);
            int p = y * WW + x;

            float dx = flow[(size_t)(b * 2 + 0) * HWPROD + p];
            float dy = flow[(size_t)(b * 2 + 1) * HWPROD + p];
            float m  = expf(metric[(size_t)b * HWPROD + p]);

            float fx = (float)x + dx;
            float fy = (float)y + dy;
            float x0f = floorf(fx), y0f = floorf(fy);
            int   x0  = (int)x0f,   y0  = (int)y0f;
            float wx1 = fx - x0f,   wy1 = fy - y0f;
            float wx0 = 1.0f - wx1, wy0 = 1.0f - wy1;

            float v[CC];
            const float* inp = in + (size_t)b * CC * HWPROD + p;
#pragma unroll
            for (int c = 0; c < CC; ++c) v[c] = inp[(size_t)c * HWPROD] * m;

            const int   xs[4] = { x0,        x0 + 1,    x0,        x0 + 1    };
            const int   ys[4] = { y0,        y0,        y0 + 1,    y0 + 1    };
            const float ws[4] = { wx0 * wy0, wx1 * wy0, wx0 * wy1, wx1 * wy1 };

#pragma unroll
            for (int k = 0; k < 4; ++k) {
                int xi = xs[k], yi = ys[k];
                // tile-membership check doubles as image-bounds check
                if ((xi >> 5) == tx && (yi >> 4) == ty) {
                    float wgt = ws[k];
                    int q = ((yi & 15) * TSX + (xi & 31)) * 17;
#pragma unroll
                    for (int c = 0; c < CC; ++c)
                        atomicAdd(&acc[q + c], v[c] * wgt);
                    atomicAdd(&acc[q + CC], m * wgt);
                }
            }
        }
    }
    __syncthreads();

    // Dense writeback + fused normalization. Tiles partition the image.
    for (int q = tid; q < TSX * TSY; q += 256) {
        int ly = q >> 5, lx = q & 31;
        int gp = (ty * TSY + ly) * WW + tx * TSX + lx;
        float inv = 1.0f / (acc[q * 17 + CC] + EPSF);
        float* op = out + (size_t)b * CC * HWPROD + gp;
#pragma unroll
        for (int c = 0; c < CC; ++c)
            op[(size_t)c * HWPROD] = acc[q * 17 + c] * inv;
    }
}

extern "C" void kernel_launch(void* const* d_in, const int* in_sizes, int n_in,
                              void* d_out, int out_size, void* d_ws, size_t ws_size,
                              hipStream_t stream) {
    const float* in     = (const float*)d_in[0];
    const float* flow   = (const float*)d_in[1];
    const float* metric = (const float*)d_in[2];
    float* out = (float*)d_out;

    unsigned int* counts = (unsigned int*)d_ws;                  // 3840 u32
    unsigned int* bins   = (unsigned int*)((char*)d_ws + 16384); // 3840*CAP u32

    hipMemsetAsync(counts, 0, NTILE * sizeof(unsigned int), stream);

    bin_kernel<<<dim3(WW / 32, HH / 8, BB), dim3(256), 0, stream>>>(flow, counts, bins);
    tile_kernel<<<dim3(NTILE), dim3(256), 0, stream>>>(in, flow, metric, counts, bins, out);
}